// Round 2
// baseline (332.445 us; speedup 1.0000x reference)
//
#include <hip/hip_runtime.h>
#include <hip/hip_bf16.h>

#define BATCH  16
#define CCH    128
#define TDIM   16384
#define MROWS  256                 // 2C
#define NCHUNK 16
#define KC     (TDIM / NCHUNK)     // 1024
#define BK     32
#define NSTEP  (KC / BK)           // 32
#define LDSP   40                  // padded LDS row stride (bf16 elems): 80 B, 16B-aligned
#define GRAM   (MROWS * MROWS)     // 65536

// ws layout (floats): [norms 4096][diag 65536][partials 16*16*65536 | gram-accum 1048576]
#define WS_NORMS 0
#define WS_DIAG  4096
#define WS_BODY  (4096 + 65536)

typedef __attribute__((ext_vector_type(8))) short bf16x8;
typedef __attribute__((ext_vector_type(4))) float f32x4;
typedef __attribute__((ext_vector_type(8))) unsigned short u16x8;

__device__ __forceinline__ unsigned short f2bf(float x) {
  unsigned int u = __float_as_uint(x);
  u += 0x7fffu + ((u >> 16) & 1u);
  return (unsigned short)(u >> 16);
}

// Partial gram of M_b = [s_b; t_b] (256 x T) over one K-chunk of KC.
// atomic_mode=0: partial -> outp + blockIdx*GRAM; diag -> diagp + blockIdx*256
// atomic_mode=1: atomicAdd into outp + b*GRAM; diag atomicAdd into diagp + b*256
__global__ __launch_bounds__(512, 2) void gram_kernel(
    const float* __restrict__ fs, const float* __restrict__ ft,
    float* __restrict__ outp, float* __restrict__ diagp, int atomic_mode)
{
  __shared__ __attribute__((aligned(16))) unsigned short sm[2][MROWS][LDSP];

  const int tid   = threadIdx.x;
  const int bidx  = blockIdx.x;
  const int b     = bidx / NCHUNK;
  const int chunk = bidx - b * NCHUNK;
  const int kbase = chunk * KC;

  const int lane = tid & 63;
  const int w    = tid >> 6;     // wave 0..7
  const int wr   = w & 3;        // rows [wr*64, +64)
  const int wc   = w >> 2;       // cols [wc*128, +128)
  const int lhi  = lane >> 4;
  const int llo  = lane & 15;
  const int koff = lhi * 8;      // bf16 elems (16 B)

  // staging: 2 threads per row, 64 B contiguous per thread per step
  const int srow = tid >> 1;          // 0..255
  const int half = tid & 1;           // 0/1 -> floats [half*16, +16) of the 32 per step
  const float* rp = ((srow < CCH)
      ? (fs + (size_t)(b * CCH + srow) * TDIM)
      : (ft + (size_t)(b * CCH + (srow - CCH)) * TDIM))
      + kbase + half * 16;

  f32x4 acc[4][8];
  #pragma unroll
  for (int i = 0; i < 4; ++i)
    #pragma unroll
    for (int j = 0; j < 8; ++j)
      acc[i][j] = (f32x4){0.f, 0.f, 0.f, 0.f};

  // prologue: step 0 -> buf0 directly
  {
    f32x4 v0 = *(const f32x4*)(rp + 0);
    f32x4 v1 = *(const f32x4*)(rp + 4);
    f32x4 v2 = *(const f32x4*)(rp + 8);
    f32x4 v3 = *(const f32x4*)(rp + 12);
    u16x8 pa, pb;
    pa[0]=f2bf(v0.x); pa[1]=f2bf(v0.y); pa[2]=f2bf(v0.z); pa[3]=f2bf(v0.w);
    pa[4]=f2bf(v1.x); pa[5]=f2bf(v1.y); pa[6]=f2bf(v1.z); pa[7]=f2bf(v1.w);
    pb[0]=f2bf(v2.x); pb[1]=f2bf(v2.y); pb[2]=f2bf(v2.z); pb[3]=f2bf(v2.w);
    pb[4]=f2bf(v3.x); pb[5]=f2bf(v3.y); pb[6]=f2bf(v3.z); pb[7]=f2bf(v3.w);
    *(u16x8*)&sm[0][srow][half * 16]     = pa;
    *(u16x8*)&sm[0][srow][half * 16 + 8] = pb;
  }
  // issue loads for step 1 into parity-1 regs
  f32x4 p[2][4];
  #pragma unroll
  for (int k = 0; k < 4; ++k)
    p[1][k] = *(const f32x4*)(rp + 1 * BK + k * 4);
  __syncthreads();

  #pragma unroll 2
  for (int s = 0; s < NSTEP; ++s) {
    const int par = s & 1;
    // issue loads for s+2 (consumed at iteration s+1) — ~1.5 steps of flight
    if (s + 2 < NSTEP) {
      #pragma unroll
      for (int k = 0; k < 4; ++k)
        p[par][k] = *(const f32x4*)(rp + (s + 2) * BK + k * 4);
    }
    // MFMA on buffer par
    {
      bf16x8 af[4], bfr[8];
      #pragma unroll
      for (int i = 0; i < 4; ++i)
        af[i] = *(const bf16x8*)&sm[par][wr * 64 + i * 16 + llo][koff];
      #pragma unroll
      for (int j = 0; j < 8; ++j)
        bfr[j] = *(const bf16x8*)&sm[par][wc * 128 + j * 16 + llo][koff];
      #pragma unroll
      for (int i = 0; i < 4; ++i)
        #pragma unroll
        for (int j = 0; j < 8; ++j)
          acc[i][j] = __builtin_amdgcn_mfma_f32_16x16x32_bf16(af[i], bfr[j], acc[i][j], 0, 0, 0);
    }
    // convert + stage data for step s+1 into buffer par^1
    if (s + 1 < NSTEP) {
      u16x8 pa, pb;
      pa[0]=f2bf(p[par^1][0].x); pa[1]=f2bf(p[par^1][0].y); pa[2]=f2bf(p[par^1][0].z); pa[3]=f2bf(p[par^1][0].w);
      pa[4]=f2bf(p[par^1][1].x); pa[5]=f2bf(p[par^1][1].y); pa[6]=f2bf(p[par^1][1].z); pa[7]=f2bf(p[par^1][1].w);
      pb[0]=f2bf(p[par^1][2].x); pb[1]=f2bf(p[par^1][2].y); pb[2]=f2bf(p[par^1][2].z); pb[3]=f2bf(p[par^1][2].w);
      pb[4]=f2bf(p[par^1][3].x); pb[5]=f2bf(p[par^1][3].y); pb[6]=f2bf(p[par^1][3].z); pb[7]=f2bf(p[par^1][3].w);
      *(u16x8*)&sm[par ^ 1][srow][half * 16]     = pa;
      *(u16x8*)&sm[par ^ 1][srow][half * 16 + 8] = pb;
    }
    __syncthreads();
  }

  // epilogue. C/D layout (m89/m91): col = lane&15, row = (lane>>4)*4 + reg
  if (atomic_mode) {
    float* out = outp + (size_t)b * GRAM;
    #pragma unroll
    for (int i = 0; i < 4; ++i) {
      int row0 = wr * 64 + i * 16 + lhi * 4;
      #pragma unroll
      for (int j = 0; j < 8; ++j) {
        int col = wc * 128 + j * 16 + llo;
        #pragma unroll
        for (int r = 0; r < 4; ++r)
          atomicAdd(&out[(size_t)(row0 + r) * MROWS + col], acc[i][j][r]);
      }
    }
    if ((wr >> 1) == wc && (llo >> 2) == lhi) {
      #pragma unroll
      for (int i = 0; i < 4; ++i) {
        float dv = (wr & 1) ? acc[i][4 + i][llo & 3] : acc[i][i][llo & 3];
        atomicAdd(&diagp[b * MROWS + wr * 64 + i * 16 + llo], dv);
      }
    }
  } else {
    float* out = outp + (size_t)bidx * GRAM;
    #pragma unroll
    for (int i = 0; i < 4; ++i) {
      int row0 = wr * 64 + i * 16 + lhi * 4;
      #pragma unroll
      for (int j = 0; j < 8; ++j) {
        int col = wc * 128 + j * 16 + llo;
        #pragma unroll
        for (int r = 0; r < 4; ++r)
          out[(size_t)(row0 + r) * MROWS + col] = acc[i][j][r];
      }
    }
    // compact diagonal of this partial (diagonal tiles live in waves with wr>>1 == wc)
    if ((wr >> 1) == wc && (llo >> 2) == lhi) {
      #pragma unroll
      for (int i = 0; i < 4; ++i) {
        float dv = (wr & 1) ? acc[i][4 + i][llo & 3] : acc[i][i][llo & 3];
        diagp[bidx * MROWS + wr * 64 + i * 16 + llo] = dv;
      }
    }
  }
}

// grid=BATCH, 256 thr: inverse norms from compact diag partials (coalesced)
__global__ __launch_bounds__(256) void norms_kernel(
    const float* __restrict__ diagp, float* __restrict__ norms, int nchunk)
{
  int b = blockIdx.x;
  int d = threadIdx.x;
  float g = 0.f;
  for (int c = 0; c < nchunk; ++c)
    g += diagp[(b * nchunk + c) * MROWS + d];
  float n = sqrtf(fmaxf(g, 0.f));
  n = fmaxf(n, 1e-12f);
  norms[b * MROWS + d] = 1.0f / n;
}

// Fused partial-reduce + normalize + signed square + global reduce.
// grid = 1024 blocks x 256 thr; each thread owns 4 consecutive gram elems of one batch.
__global__ __launch_bounds__(256) void loss_kernel(
    const float* __restrict__ body, const float* __restrict__ norms,
    float* __restrict__ out, int nchunk)
{
  int flat = blockIdx.x * 1024 + threadIdx.x * 4;   // element index into (b, 65536)
  int b    = flat >> 16;
  int e    = flat & 65535;
  const float* nb = norms + b * MROWS;

  f32x4 g = (f32x4){0.f, 0.f, 0.f, 0.f};
  const float* src = body + (size_t)b * nchunk * GRAM + e;
  #pragma unroll 4
  for (int c = 0; c < nchunk; ++c) {
    f32x4 v = *(const f32x4*)(src + (size_t)c * GRAM);
    g.x += v.x; g.y += v.y; g.z += v.z; g.w += v.w;
  }
  int i  = e >> 8;
  int j0 = e & 255;
  float ri = nb[i];
  f32x4 rj = *(const f32x4*)(nb + j0);   // j0 is 4-aligned
  float si = (i < CCH) ? 1.f : -1.f;
  float accl = 0.f;
  #pragma unroll
  for (int q = 0; q < 4; ++q) {
    int j = j0 + q;
    float gh = g[q] * ri * rj[q];
    float sgn = ((j < CCH) ? 1.f : -1.f) * si;
    accl += sgn * gh * gh;
  }
  #pragma unroll
  for (int off = 32; off > 0; off >>= 1)
    accl += __shfl_down(accl, off, 64);
  __shared__ float red[4];
  if ((threadIdx.x & 63) == 0) red[threadIdx.x >> 6] = accl;
  __syncthreads();
  if (threadIdx.x == 0) {
    float t = red[0] + red[1] + red[2] + red[3];
    atomicAdd(out, t * (1.0f / (float)(BATCH * CCH * CCH)));
  }
}

extern "C" void kernel_launch(void* const* d_in, const int* in_sizes, int n_in,
                              void* d_out, int out_size, void* d_ws, size_t ws_size,
                              hipStream_t stream) {
  const float* fs = (const float*)d_in[0];
  const float* ft = (const float*)d_in[1];
  float* out   = (float*)d_out;
  float* wsf   = (float*)d_ws;
  float* norms = wsf + WS_NORMS;
  float* diagp = wsf + WS_DIAG;
  float* body  = wsf + WS_BODY;

  const size_t need_partials =
      (size_t)(WS_BODY + (size_t)BATCH * NCHUNK * GRAM) * sizeof(float);
  const int atomic_mode = (ws_size >= need_partials) ? 0 : 1;
  const int nchunk = atomic_mode ? 1 : NCHUNK;

  (void)hipMemsetAsync(d_out, 0, sizeof(float), stream);
  if (atomic_mode) {
    // zero diag (4096 used) + gram accumulator (4 MB), contiguous from diagp
    (void)hipMemsetAsync(diagp, 0,
        (size_t)(65536 + (size_t)BATCH * GRAM) * sizeof(float), stream);
  }

  gram_kernel<<<dim3(BATCH * NCHUNK), dim3(512), 0, stream>>>(fs, ft, body, diagp, atomic_mode);
  norms_kernel<<<dim3(BATCH), dim3(256), 0, stream>>>(diagp, norms, nchunk);
  loss_kernel<<<dim3(1024), dim3(256), 0, stream>>>(body, norms, out, nchunk);
}